// Round 1
// baseline (879.790 us; speedup 1.0000x reference)
//
#include <hip/hip_runtime.h>

#define M_ROWS 16384

struct PackArgs {
  const float* W[6];
  const float* b[6];
};

// One block per output row across all 6 layers. Packs sign bits of W rows
// (bit k of word w = sign(W[n][32w+k']), natural mapping k = 64*chunk + lane)
// and sign of bias. Pad bits (k >= K) are 0 in both A and B packs, so they
// contribute 0 to popcount(xor).
__global__ __launch_bounds__(256) void pack_w_kernel(PackArgs a, unsigned* B1, unsigned* By, int* bs)
{
  int blk = blockIdx.x;
  int l, n;
  if      (blk < 500)  { l = 0; n = blk; }
  else if (blk < 900)  { l = 1; n = blk - 500; }
  else if (blk < 1250) { l = 2; n = blk - 900; }
  else if (blk < 1550) { l = 3; n = blk - 1250; }
  else if (blk < 1850) { l = 4; n = blk - 1550; }
  else                 { l = 5; n = blk - 1850; }
  const int Ks[6] = {4096, 500, 400, 350, 300, 300};
  int K = Ks[l];
  int KW = (l == 0) ? 128 : 16;
  unsigned* Bout = (l == 0) ? B1 : (By + (size_t)(l - 1) * 512 * 16);
  const float* Wrow = a.W[l] + (size_t)n * K;
  int lane = threadIdx.x & 63;
  int wv = threadIdx.x >> 6;
  int chunks = KW / 2;  // 64-bit chunks
  for (int c = wv; c < chunks; c += 4) {
    int k = c * 64 + lane;
    bool pred = false;
    if (k < K) pred = (Wrow[k] >= 0.0f);
    unsigned long long m = __ballot(pred);
    if (lane == 0) {
      Bout[(size_t)n * KW + 2 * c]     = (unsigned)m;
      Bout[(size_t)n * KW + 2 * c + 1] = (unsigned)(m >> 32);
    }
  }
  if (threadIdx.x == 0) bs[l * 512 + n] = (a.b[l][n] >= 0.0f) ? 1 : -1;
}

// Layer 1: reads x (fp32) once, ballot-packs sign bits into LDS, then
// XOR-popcount bit-GEMM vs packed W1. Writes y1 (int16) + integer column
// sum / sumsq via atomics (exact, deterministic).
__global__ __launch_bounds__(256) void gemm1_kernel(const float* __restrict__ x,
    const unsigned* __restrict__ B1, const int* __restrict__ bs1,
    short* __restrict__ y1, int* __restrict__ gs, unsigned long long* __restrict__ gq)
{
  __shared__ __align__(16) unsigned Abits[32 * 128];   // 16 KB: 32 rows x 4096 bits
  __shared__ __align__(16) unsigned Bsw[256 * 32];     // 32 KB: 256 cols x 1024-bit K-chunk (xor-swizzled)
  __shared__ int red_s[256];
  __shared__ int red_q[256];
  int tid = threadIdx.x;
  int lane = tid & 63, wv = tid >> 6;
  int cg = tid & 31, rg = tid >> 5;
  int row0 = blockIdx.x * 32;

  // ---- stage A bits: 32 rows x 64 chunks of 64 elems; batch 8 loads for MLP ----
  for (int i0 = wv * 512; i0 < wv * 512 + 512; i0 += 8) {
    int r = i0 >> 6;
    int cb = i0 & 63;
    const float* xp = x + (size_t)(row0 + r) * 4096 + cb * 64 + lane;
    float v[8];
#pragma unroll
    for (int u = 0; u < 8; u++) v[u] = xp[u * 64];
    unsigned long long mm[8];
#pragma unroll
    for (int u = 0; u < 8; u++) mm[u] = __ballot(v[u] >= 0.0f);
    if (lane == 0) {
#pragma unroll
      for (int u = 0; u < 8; u++)
        *(unsigned long long*)&Abits[r * 128 + 2 * (cb + u)] = mm[u];
    }
  }

  for (int pass = 0; pass < 2; pass++) {
    int colbase = pass * 256;
    unsigned acc[4][8];
#pragma unroll
    for (int r = 0; r < 4; r++)
#pragma unroll
      for (int j = 0; j < 8; j++) acc[r][j] = 0;

    for (int kc = 0; kc < 4; kc++) {
      __syncthreads();
      // stage B K-chunk: 256 cols x 32 words, xor-swizzle 16B groups for bank spread
#pragma unroll
      for (int i = 0; i < 8; i++) {
        int q = i * 256 + tid;
        int c = q >> 3;
        int w4 = (q & 7) << 2;
        uint4 bv = *(const uint4*)(B1 + (size_t)(colbase + c) * 128 + kc * 32 + w4);
        int g = (w4 >> 2) ^ (c & 7);
        *(uint4*)&Bsw[c * 32 + 4 * g] = bv;
      }
      __syncthreads();
#pragma unroll
      for (int w4 = 0; w4 < 32; w4 += 4) {
        uint4 av[4];
#pragma unroll
        for (int r = 0; r < 4; r++)
          av[r] = *(const uint4*)&Abits[(rg * 4 + r) * 128 + kc * 32 + w4];
#pragma unroll
        for (int jj = 0; jj < 8; jj++) {
          int c = jj * 32 + cg;
          int g = (w4 >> 2) ^ (c & 7);
          uint4 bv = *(const uint4*)&Bsw[c * 32 + 4 * g];
#pragma unroll
          for (int r = 0; r < 4; r++)
            acc[r][jj] += __popc(av[r].x ^ bv.x) + __popc(av[r].y ^ bv.y)
                        + __popc(av[r].z ^ bv.z) + __popc(av[r].w ^ bv.w);
        }
      }
    }
    // ---- epilogue for this 256-col pass ----
    red_s[tid] = 0; red_q[tid] = 0;
    __syncthreads();
#pragma unroll
    for (int jj = 0; jj < 8; jj++) {
      int col = colbase + jj * 32 + cg;
      int bsv = (col < 500) ? bs1[col] : 0;
      int s = 0, q = 0;
#pragma unroll
      for (int r = 0; r < 4; r++) {
        int y = 4096 - 2 * (int)acc[r][jj] + bsv;
        if (col < 500)
          y1[(size_t)(row0 + rg * 4 + r) * 500 + col] = (short)y;
        s += y; q += y * y;
      }
      atomicAdd(&red_s[jj * 32 + cg], s);
      atomicAdd(&red_q[jj * 32 + cg], q);
    }
    __syncthreads();
    {
      int col = colbase + tid;
      if (col < 500) {
        atomicAdd(&gs[col], red_s[tid]);
        atomicAdd(&gq[col], (unsigned long long)(long long)red_q[tid]);
      }
    }
  }
}

// Layers 2..6: binarize previous y on the fly (threshold from prev-layer
// integer stats + gamma/beta), then XOR-popcount bit-GEMM. Layer 6 writes
// fp32 d_out instead of y/stats.
__global__ __launch_bounds__(256) void gemmy_kernel(
    const short* __restrict__ yin, int strin, int Kin,
    const int* __restrict__ gs_in, const unsigned long long* __restrict__ gq_in,
    const float* __restrict__ g_in, const float* __restrict__ be_in,
    const unsigned* __restrict__ Bb, const int* __restrict__ bsl,
    int Nout, int strout, int passes,
    short* __restrict__ yout, int* __restrict__ gs_out, unsigned long long* __restrict__ gq_out,
    float* __restrict__ fout, int is_final)
{
  __shared__ __align__(16) unsigned Abits[32 * 16];   // 2 KB
  __shared__ __align__(16) unsigned Bsw[256 * 16];    // 16 KB per col-pass
  __shared__ float thr_t[512], thr_g[512], thr_c[512];
  __shared__ int red_s[256], red_q[256];
  int tid = threadIdx.x;
  int lane = tid & 63, wv = tid >> 6;
  int cg = tid & 31, rg = tid >> 5;
  int row0 = blockIdx.x * 32;

  // thresholds: bit = ((y - t)*sg + c) >= 0 reproduces sign(bn(y)) exactly
  for (int k = tid; k < 512; k += 256) {
    float t = 0.f, sg = 0.f, cc = -1.f;
    if (k < Kin) {
      float m  = (float)gs_in[k] * (1.0f / 16384.0f);
      float ms = (float)gq_in[k] * (1.0f / 16384.0f);
      float var = fmaxf(ms - m * m, 0.0f);
      float g = g_in[k], be = be_in[k];
      if (g != 0.0f) {
        t = m - be * sqrtf(var + 1e-5f) / g;
        sg = (g > 0.0f) ? 1.0f : -1.0f;
        cc = 0.0f;
      } else { t = 0.0f; sg = 0.0f; cc = be; }
    }
    thr_t[k] = t; thr_g[k] = sg; thr_c[k] = cc;
  }
  __syncthreads();

  // stage A bits: 32 rows x 8 chunks (512 padded bits), guarded k < Kin
  for (int i0 = wv * 64; i0 < wv * 64 + 64; i0 += 4) {
    int r = i0 >> 3;
    int cb = i0 & 7;
    float v[4];
#pragma unroll
    for (int u = 0; u < 4; u++) {
      int k = (cb + u) * 64 + lane;
      v[u] = (k < Kin) ? (float)yin[(size_t)(row0 + r) * strin + k] : -1.0f;
    }
#pragma unroll
    for (int u = 0; u < 4; u++) {
      int k = (cb + u) * 64 + lane;
      bool p = false;
      if (k < Kin) p = ((v[u] - thr_t[k]) * thr_g[k] + thr_c[k]) >= 0.0f;
      unsigned long long m = __ballot(p);
      if (lane == 0)
        *(unsigned long long*)&Abits[r * 16 + 2 * (cb + u)] = m;
    }
  }

  for (int pass = 0; pass < passes; pass++) {
    int colbase = pass * 256;
    __syncthreads();
#pragma unroll
    for (int i = 0; i < 4; i++) {
      int q = i * 256 + tid;
      int c = q >> 2;
      int w4 = (q & 3) << 2;
      uint4 bv = *(const uint4*)(Bb + (size_t)(colbase + c) * 16 + w4);
      int g = (w4 >> 2) ^ (c & 3);
      *(uint4*)&Bsw[c * 16 + 4 * g] = bv;
    }
    __syncthreads();
    unsigned acc[4][8];
#pragma unroll
    for (int r = 0; r < 4; r++)
#pragma unroll
      for (int j = 0; j < 8; j++) acc[r][j] = 0;
#pragma unroll
    for (int w4 = 0; w4 < 16; w4 += 4) {
      uint4 av[4];
#pragma unroll
      for (int r = 0; r < 4; r++)
        av[r] = *(const uint4*)&Abits[(rg * 4 + r) * 16 + w4];
#pragma unroll
      for (int jj = 0; jj < 8; jj++) {
        int c = jj * 32 + cg;
        int g = (w4 >> 2) ^ (c & 3);
        uint4 bv = *(const uint4*)&Bsw[c * 16 + 4 * g];
#pragma unroll
        for (int r = 0; r < 4; r++)
          acc[r][jj] += __popc(av[r].x ^ bv.x) + __popc(av[r].y ^ bv.y)
                      + __popc(av[r].z ^ bv.z) + __popc(av[r].w ^ bv.w);
      }
    }
    // epilogue
    red_s[tid] = 0; red_q[tid] = 0;
    __syncthreads();
#pragma unroll
    for (int jj = 0; jj < 8; jj++) {
      int col = colbase + jj * 32 + cg;
      int bsv = (col < Nout) ? bsl[col] : 0;
      int s = 0, q = 0;
#pragma unroll
      for (int r = 0; r < 4; r++) {
        int y = Kin - 2 * (int)acc[r][jj] + bsv;
        if (col < Nout) {
          if (is_final) fout[(size_t)(row0 + rg * 4 + r) * Nout + col] = (float)y;
          else          yout[(size_t)(row0 + rg * 4 + r) * strout + col] = (short)y;
        }
        s += y; q += y * y;
      }
      if (!is_final) {
        atomicAdd(&red_s[jj * 32 + cg], s);
        atomicAdd(&red_q[jj * 32 + cg], q);
      }
    }
    if (!is_final) {
      __syncthreads();
      int col = colbase + tid;
      if (col < Nout) {
        atomicAdd(&gs_out[col], red_s[tid]);
        atomicAdd(&gq_out[col], (unsigned long long)(long long)red_q[tid]);
      }
    }
  }
}

extern "C" void kernel_launch(void* const* d_in, const int* in_sizes, int n_in,
                              void* d_out, int out_size, void* d_ws, size_t ws_size,
                              hipStream_t stream)
{
  (void)in_sizes; (void)n_in; (void)out_size; (void)ws_size;
  char* ws = (char*)d_ws;
  // workspace layout (bytes):
  //   B1 bits:      0      .. 262144   (512 rows x 128 words)
  //   B2..B6 bits:  262144 .. 425984   (5 x 512 rows x 16 words)
  //   bias signs:   425984 .. 438272   (6 x 512 int)
  //   col sums:     438272 .. 448512   (5 x 512 int)
  //   col sumsq:    448512 .. 468992   (5 x 512 u64)
  //   yA, yB:       471040 ..          (2 x 16384 x 512 int16 = 33.5 MB)
  unsigned* B1 = (unsigned*)(ws);
  unsigned* By = (unsigned*)(ws + 262144);
  int* bs      = (int*)(ws + 425984);
  int* gs      = (int*)(ws + 438272);
  unsigned long long* gq = (unsigned long long*)(ws + 448512);
  short* yA = (short*)(ws + 471040);
  short* yB = yA + (size_t)16384 * 512;

  hipMemsetAsync(ws + 438272, 0, 30720, stream);  // zero all stats

  PackArgs pa;
  pa.W[0] = (const float*)d_in[1];  pa.b[0] = (const float*)d_in[2];
  pa.W[1] = (const float*)d_in[5];  pa.b[1] = (const float*)d_in[6];
  pa.W[2] = (const float*)d_in[9];  pa.b[2] = (const float*)d_in[10];
  pa.W[3] = (const float*)d_in[13]; pa.b[3] = (const float*)d_in[14];
  pa.W[4] = (const float*)d_in[17]; pa.b[4] = (const float*)d_in[18];
  pa.W[5] = (const float*)d_in[21]; pa.b[5] = (const float*)d_in[22];

  pack_w_kernel<<<1885, 256, 0, stream>>>(pa, B1, By, bs);
  gemm1_kernel<<<512, 256, 0, stream>>>((const float*)d_in[0], B1, bs, yA, gs, gq);

  // layer 2: y1(K=500) -> y2(N=400)
  gemmy_kernel<<<512, 256, 0, stream>>>(yA, 500, 500, gs, gq,
      (const float*)d_in[3], (const float*)d_in[4],
      By + 0 * 512 * 16, bs + 512, 400, 400, 2,
      yB, gs + 512, gq + 512, nullptr, 0);
  // layer 3: y2(400) -> y3(350, stride 352)
  gemmy_kernel<<<512, 256, 0, stream>>>(yB, 400, 400, gs + 512, gq + 512,
      (const float*)d_in[7], (const float*)d_in[8],
      By + 1 * 512 * 16, bs + 1024, 350, 352, 2,
      yA, gs + 1024, gq + 1024, nullptr, 0);
  // layer 4: y3(350) -> y4(300)
  gemmy_kernel<<<512, 256, 0, stream>>>(yA, 352, 350, gs + 1024, gq + 1024,
      (const float*)d_in[11], (const float*)d_in[12],
      By + 2 * 512 * 16, bs + 1536, 300, 300, 2,
      yB, gs + 1536, gq + 1536, nullptr, 0);
  // layer 5: y4(300) -> y5(300)
  gemmy_kernel<<<512, 256, 0, stream>>>(yB, 300, 300, gs + 1536, gq + 1536,
      (const float*)d_in[15], (const float*)d_in[16],
      By + 3 * 512 * 16, bs + 2048, 300, 300, 2,
      yA, gs + 2048, gq + 2048, nullptr, 0);
  // layer 6: y5(300) -> out(35), fp32, no stats
  gemmy_kernel<<<512, 256, 0, stream>>>(yA, 300, 300, gs + 2048, gq + 2048,
      (const float*)d_in[19], (const float*)d_in[20],
      By + 4 * 512 * 16, bs + 2560, 35, 35, 1,
      nullptr, nullptr, nullptr, (float*)d_out, 1);
}